// Round 1
// 291.555 us; speedup vs baseline: 1.6407x; 1.6407x over previous
//
#include <hip/hip_runtime.h>

// Problem constants
#define BN    65536    // B*N rows
#define DD    256      // D
#define KCB   512      // codebook entries
#define MT    32       // rows per block
#define NCH   8        // D chunks of 32
#define TPW   8        // 16-code tiles per wave (4 waves x 8 x 16 = 512 codes)
#define NBLK  2048     // BN/MT

typedef __attribute__((ext_vector_type(8))) short bf16x8;
typedef __attribute__((ext_vector_type(4))) float f32x4;

__device__ __forceinline__ float bf2f(unsigned short u) {
  return __uint_as_float(((unsigned int)u) << 16);
}
__device__ __forceinline__ unsigned short f2bf(float f) {
  unsigned int u = __float_as_uint(f);
  return (unsigned short)((u + 0x7fffu + ((u >> 16) & 1u)) >> 16);  // RNE
}

__global__ void vq_zero_ws(float* ws) { ws[0] = 0.f; }

// ---- one-shot codebook prep: fp32 -> bf16 hi/lo split + fp64-exact e_sq ----
// grid 128 x 256: wave w of block b handles code b*4+w (64 float4 per code)
__global__ void vq_prep(const float* __restrict__ cbg,
                        unsigned short* __restrict__ cbh,
                        unsigned short* __restrict__ cbl,
                        float* __restrict__ esq) {
  const int tid = threadIdx.x, lane = tid & 63, wave = tid >> 6;
  const int code = blockIdx.x * 4 + wave;
  float4 v = ((const float4*)cbg)[(size_t)code * 64 + lane];
  ushort4 h, l;
  h.x = f2bf(v.x); l.x = f2bf(v.x - bf2f(h.x));
  h.y = f2bf(v.y); l.y = f2bf(v.y - bf2f(h.y));
  h.z = f2bf(v.z); l.z = f2bf(v.z - bf2f(h.z));
  h.w = f2bf(v.w); l.w = f2bf(v.w - bf2f(h.w));
  *(ushort4*)&cbh[(size_t)code * 256 + lane * 4] = h;
  *(ushort4*)&cbl[(size_t)code * 256 + lane * 4] = l;
  double s = (double)v.x * v.x + (double)v.y * v.y +
             (double)v.z * v.z + (double)v.w * v.w;
#pragma unroll
  for (int m = 1; m < 64; m <<= 1) s += __shfl_xor(s, m, 64);
  if (lane == 0) esq[code] = (float)s;
}

// ---- main kernel. PREP=1: bf16 codebook + esq precomputed in workspace.
//      PREP=0: self-sufficient fallback (in-register conversion).
template <int PREP>
__global__ __launch_bounds__(256, 3) void vq_main(
    const float* __restrict__ zg,    // (BN, D) float32
    const int* __restrict__ maskg,   // (BN) mask, dtype probed
    const float* __restrict__ cbg,   // (K, D) float32
    const unsigned short* __restrict__ cbh,  // (K, D) bf16 hi   [PREP]
    const unsigned short* __restrict__ cbl,  // (K, D) bf16 lo   [PREP]
    const float* __restrict__ esqg,          // (K) fp64-acc esq [PREP]
    float* __restrict__ outq,        // (BN, D) float32
    float* __restrict__ outidx,      // (BN) float32 (-1 pad)
    float* __restrict__ wsum)        // d_ws fp32 accumulator
{
  // ~37 KB LDS -> 3 blocks/CU (VGPR-capped), 4 by LDS
  __shared__ unsigned short zs_hi[NCH * MT * 32];   // 16 KB [ch][row][32]
  __shared__ unsigned short zs_lo[NCH * MT * 32];   // 16 KB
  __shared__ float esqs[KCB];                       // 2 KB
  __shared__ float zsq[MT];
  __shared__ float wv1[4][MT], wv2[4][MT];
  __shared__ int   wi1[4][MT];
  __shared__ float carr[MT];
  __shared__ int   fidxs[MT], maskb[MT], flaglist[MT];
  __shared__ int   flagcnt, mflags;
  __shared__ double rbd[4];
  __shared__ int    rbi[4];

  const int tid  = threadIdx.x;
  const int lane = tid & 63;
  const int wave = tid >> 6;
  const int q    = lane >> 4;
  const int l15  = lane & 15;
  const int m0   = blockIdx.x * MT;

  if (tid == 0) { flagcnt = 0; mflags = 0; }

  // ---- mask dtype probe on first 512 bytes (in-bounds under every layout) --
  int wm = 0;
  if (tid < 128) {
    unsigned int W = ((const unsigned int*)maskg)[tid];
    if (W > 1u) wm |= 1;
    if (W != 0u && W != 0x3f800000u) wm |= 2;
    unsigned int lo = W & 0xffffu, hi = W >> 16;
    if ((lo != 0u && lo != 0x3f80u) || (hi != 0u && hi != 0x3f80u)) wm |= 4;
  }
  if (wm) atomicOr(&mflags, wm);

  // ---- esq into LDS ----
  if (PREP) {
    esqs[tid]       = esqg[tid];
    esqs[tid + 256] = esqg[tid + 256];
  }

  // ---- stage z tile: 32 rows x 256 fp32 -> hi/lo bf16; fused z_sq reduce ---
#pragma unroll
  for (int i = 0; i < 8; ++i) {
    int idx = i * 256 + tid;            // float4 index: 32 rows x 64
    int row = idx >> 6;                 // = i*4 + wave
    int f4  = idx & 63;
    float4 v = ((const float4*)zg)[(size_t)(m0 + row) * 64 + f4];
    int ch  = f4 >> 3;
    int col = (f4 & 7) * 4;
    int base = (ch * MT + row) * 32 + col;
    ushort4 h, l;
    h.x = f2bf(v.x); l.x = f2bf(v.x - bf2f(h.x));
    h.y = f2bf(v.y); l.y = f2bf(v.y - bf2f(h.y));
    h.z = f2bf(v.z); l.z = f2bf(v.z - bf2f(h.z));
    h.w = f2bf(v.w); l.w = f2bf(v.w - bf2f(h.w));
    *(ushort4*)&zs_hi[base] = h;
    *(ushort4*)&zs_lo[base] = l;
    // z_sq: whole wave holds one row per i -> 64-lane shuffle reduce
    float s = v.x * v.x + v.y * v.y + v.z * v.z + v.w * v.w;
#pragma unroll
    for (int m = 1; m < 64; m <<= 1) s += __shfl_xor(s, m, 64);
    if (lane == 0) zsq[row] = s;
  }

  if (!PREP) {
    // fallback: per-block esq (fp32, matches old kernel's accuracy envelope)
    for (int c = tid; c < KCB; c += 256) {
      float s = 0.f;
      for (int f4i = 0; f4i < 64; ++f4i) {
        float4 v = ((const float4*)cbg)[(size_t)c * 64 + f4i];
        s = fmaf(v.x, v.x, s); s = fmaf(v.y, v.y, s);
        s = fmaf(v.z, v.z, s); s = fmaf(v.w, v.w, s);
      }
      esqs[c] = s;
    }
  }
  __syncthreads();
  const int mmode = mflags;

  // ---------------- barrier-free main compute -------------------------------
  // Wave owns 8 disjoint 16-code tiles. 3-pass split-bf16 dot accumulated in
  // ONE set of accumulators: zh*eh + zl*eh + zh*el (lo*lo dropped, ~1e-4 err,
  // covered by the 0.02 fp64-rescan threshold).
  f32x4 acc[TPW][2];
#pragma unroll
  for (int t = 0; t < TPW; ++t)
#pragma unroll
    for (int i = 0; i < 2; ++i)
      acc[t][i] = (f32x4){0.f, 0.f, 0.f, 0.f};

  const unsigned short* Abh = &zs_hi[l15 * 32 + q * 8];
  const unsigned short* Abl = &zs_lo[l15 * 32 + q * 8];

  for (int kk = 0; kk < NCH; ++kk) {
    bf16x8 ah0 = *(const bf16x8*)(Abh + kk * 1024);
    bf16x8 ah1 = *(const bf16x8*)(Abh + kk * 1024 + 512);
    bf16x8 al0 = *(const bf16x8*)(Abl + kk * 1024);
    bf16x8 al1 = *(const bf16x8*)(Abl + kk * 1024 + 512);
#pragma unroll
    for (int t = 0; t < TPW; ++t) {
      const int code_row = (wave * TPW + t) * 16 + l15;
      bf16x8 bh, bl;
      if (PREP) {
        const size_t e = (size_t)code_row * 256 + kk * 32 + q * 8;
        bh = *(const bf16x8*)&cbh[e];
        bl = *(const bf16x8*)&cbl[e];
      } else {
        const float* src = &cbg[(size_t)code_row * 256 + kk * 32 + q * 8];
        float4 v0 = *(const float4*)src;
        float4 v1 = *(const float4*)(src + 4);
        float f[8] = {v0.x, v0.y, v0.z, v0.w, v1.x, v1.y, v1.z, v1.w};
        union { ushort us[8]; bf16x8 v; } H, L;
#pragma unroll
        for (int e = 0; e < 8; ++e) {
          unsigned short hh = f2bf(f[e]);
          H.us[e] = hh;
          L.us[e] = f2bf(f[e] - bf2f(hh));
        }
        bh = H.v; bl = L.v;
      }
      acc[t][0] = __builtin_amdgcn_mfma_f32_16x16x32_bf16(ah0, bh, acc[t][0], 0, 0, 0);
      acc[t][1] = __builtin_amdgcn_mfma_f32_16x16x32_bf16(ah1, bh, acc[t][1], 0, 0, 0);
      acc[t][0] = __builtin_amdgcn_mfma_f32_16x16x32_bf16(al0, bh, acc[t][0], 0, 0, 0);
      acc[t][1] = __builtin_amdgcn_mfma_f32_16x16x32_bf16(al1, bh, acc[t][1], 0, 0, 0);
      acc[t][0] = __builtin_amdgcn_mfma_f32_16x16x32_bf16(ah0, bl, acc[t][0], 0, 0, 0);
      acc[t][1] = __builtin_amdgcn_mfma_f32_16x16x32_bf16(ah1, bl, acc[t][1], 0, 0, 0);
    }
  }

  // ---- fold: per-thread running top-2 over the wave's 128 codes -----------
  // C layout: col=l15 (code), row=i*16+q*4+rr  [m89-verified, as before]
  float t1[2][4], t2[2][4];
  int   ti[2][4];
#pragma unroll
  for (int i = 0; i < 2; ++i)
#pragma unroll
    for (int rr = 0; rr < 4; ++rr) { t1[i][rr] = 3.0e38f; t2[i][rr] = 3.0e38f; ti[i][rr] = 0; }

#pragma unroll
  for (int t = 0; t < TPW; ++t) {
    const int code = (wave * TPW + t) * 16 + l15;
    const float eh = 0.5f * esqs[code];
#pragma unroll
    for (int i = 0; i < 2; ++i)
#pragma unroll
      for (int rr = 0; rr < 4; ++rr) {
        float v = eh - acc[t][i][rr];      // half-score; strict < keeps low idx
        bool  tk = v < t1[i][rr];
        float m2 = fminf(t2[i][rr], v);
        t2[i][rr] = tk ? t1[i][rr] : m2;
        ti[i][rr] = tk ? code : ti[i][rr];
        t1[i][rr] = tk ? v : t1[i][rr];
      }
  }

  // ---- reduce across the 16 lanes (l15) sharing the same rows --------------
#pragma unroll
  for (int i = 0; i < 2; ++i)
#pragma unroll
    for (int rr = 0; rr < 4; ++rr) {
      float a1 = t1[i][rr], a2 = t2[i][rr];
      int   ai = ti[i][rr];
#pragma unroll
      for (int m = 1; m < 16; m <<= 1) {
        float o1 = __shfl_xor(a1, m, 64);
        float o2 = __shfl_xor(a2, m, 64);
        int   oi = __shfl_xor(ai, m, 64);
        bool  tk = (o1 < a1) || (o1 == a1 && oi < ai);
        float losr = tk ? a1 : o1;
        a2 = fminf(fminf(a2, o2), losr);
        a1 = tk ? o1 : a1;
        ai = tk ? oi : ai;
      }
      if (l15 == 0) {
        int row = i * 16 + q * 4 + rr;
        wv1[wave][row] = a1; wv2[wave][row] = a2; wi1[wave][row] = ai;
      }
    }
  __syncthreads();

  // ---- per-row merge of 4 wave candidates + finalize ----------------------
  if (tid < MT) {
    float bv1 = 3.0e38f, bv2 = 3.0e38f;
    int   bi = 0x7fffffff;
#pragma unroll
    for (int w = 0; w < 4; ++w) {
      float a1 = wv1[w][tid], a2 = wv2[w][tid];
      int   ai = wi1[w][tid];
      bool  tk = (a1 < bv1) || (a1 == bv1 && ai < bi);
      if (tk) { bv2 = fminf(bv1, a2); bv1 = a1; bi = ai; }
      else    { bv2 = fminf(bv2, a1); }
    }
    fidxs[tid] = bi;
    carr[tid]  = zsq[tid] + 2.f * bv1;    // min ||z-e||^2
    if (2.f * (bv2 - bv1) < 0.02f) {      // near-tie -> exact fp64 rescan
      int pos = atomicAdd(&flagcnt, 1);
      flaglist[pos] = tid;
    }
    int mk;
    if (!(mmode & 1))      mk = maskg[m0 + tid] ? 1 : 0;                          // int32
    else if (!(mmode & 2)) mk = ((const float*)maskg)[m0 + tid] != 0.f ? 1 : 0;   // fp32
    else if (!(mmode & 4)) mk = ((const unsigned short*)maskg)[m0 + tid] ? 1 : 0; // bf16
    else                   mk = ((const unsigned char*)maskg)[m0 + tid] ? 1 : 0;  // bool
    maskb[tid] = mk;
  }
  __syncthreads();

  // ---- exact fp64 rescan of near-tie rows (global fp32 reads, rare) -------
  int nflag = flagcnt;
  for (int f = 0; f < nflag; ++f) {
    int row = flaglist[f];
    double bd = 1e300;
    int    bk = 0;
    for (int k = tid; k < KCB; k += 256) {
      double d2 = 0.0;
      for (int d = 0; d < DD; ++d) {
        double df = (double)zg[(size_t)(m0 + row) * DD + d] - (double)cbg[(size_t)k * DD + d];
        d2 = fma(df, df, d2);
      }
      if (d2 < bd) { bd = d2; bk = k; }
    }
    for (int m = 1; m < 64; m <<= 1) {
      double od = __shfl_xor(bd, m, 64);
      int    ok = __shfl_xor(bk, m, 64);
      if (od < bd || (od == bd && ok < bk)) { bd = od; bk = ok; }
    }
    if (lane == 0) { rbd[wave] = bd; rbi[wave] = bk; }
    __syncthreads();
    if (tid == 0) {
      double xd = rbd[0]; int xk = rbi[0];
      for (int w = 1; w < 4; ++w)
        if (rbd[w] < xd || (rbd[w] == xd && rbi[w] < xk)) { xd = rbd[w]; xk = rbi[w]; }
      fidxs[row] = xk;
      carr[row]  = (float)xd;
    }
    __syncthreads();
  }
  __syncthreads();

  // ---- index output: float32 values, -1.0 pad ----
  if (tid < MT)
    outidx[m0 + tid] = maskb[tid] ? (float)(fidxs[tid] & (KCB - 1)) : -1.0f;

  // ---- commit partial -> device atomicAdd ----
  if (wave == 0) {
    float c = (lane < MT) ? carr[lane] : 0.f;
    for (int m = 1; m < 64; m <<= 1) c += __shfl_xor(c, m, 64);
    if (lane == 0) atomicAdd(wsum, c);
  }

  // ---- quantized output: float32 codebook gather, masked ----
#pragma unroll
  for (int i = 0; i < 8; ++i) {
    int idx = i * 256 + tid;            // float4 index: 32 rows x 64
    int row = idx >> 6;
    int f4  = idx & 63;
    int k   = fidxs[row] & (KCB - 1);
    float4 val = {0.f, 0.f, 0.f, 0.f};
    if (maskb[row]) val = ((const float4*)cbg)[(size_t)k * 64 + f4];
    ((float4*)outq)[(size_t)(m0 + row) * 64 + f4] = val;
  }
}

__global__ void vq_final(const float* __restrict__ wsum,
                         float* __restrict__ outloss) {
  if (threadIdx.x == 0)
    outloss[0] = 0.25f * (wsum[0] / 16777216.0f);   // mean over B*N*D
}

extern "C" void kernel_launch(void* const* d_in, const int* in_sizes, int n_in,
                              void* d_out, int out_size, void* d_ws, size_t ws_size,
                              hipStream_t stream) {
  // Inputs identified by element count (harness order alphabetical:
  // codebook, phoneme_mask, z — confirmed in earlier rounds). z/codebook
  // FLOAT32, mask dtype probed on-device.
  const void* pz = d_in[0];
  const void* pm = (n_in > 1) ? d_in[1] : d_in[0];
  const void* pc = (n_in > 2) ? d_in[2] : d_in[0];
  for (int i = 0; i < n_in; ++i) {
    if      (in_sizes[i] == BN * DD)  pz = d_in[i];
    else if (in_sizes[i] == BN)       pm = d_in[i];
    else if (in_sizes[i] == KCB * DD) pc = d_in[i];
  }
  const float* zg  = (const float*)pz;
  const int*   mk  = (const int*)pm;
  const float* cbg = (const float*)pc;

  float* outq   = (float*)d_out;
  float* outidx = outq + (size_t)BN * DD;
  float* outls  = outidx + BN;
  float* wsum   = (float*)d_ws;

  // workspace layout: [0] wsum | +1024 esq (2KB) | +4096 cb_hi (256KB) | cb_lo
  const size_t ESQ_OFF = 1024;
  const size_t CBH_OFF = 4096;
  const size_t CBL_OFF = 4096 + (size_t)KCB * DD * 2;
  const size_t WS_NEED = CBL_OFF + (size_t)KCB * DD * 2;

  vq_zero_ws<<<1, 1, 0, stream>>>(wsum);
  if (ws_size >= WS_NEED) {
    unsigned short* cbh = (unsigned short*)((char*)d_ws + CBH_OFF);
    unsigned short* cbl = (unsigned short*)((char*)d_ws + CBL_OFF);
    float*          esw = (float*)((char*)d_ws + ESQ_OFF);
    vq_prep<<<128, 256, 0, stream>>>(cbg, cbh, cbl, esw);
    vq_main<1><<<NBLK, 256, 0, stream>>>(zg, mk, cbg, cbh, cbl, esw,
                                         outq, outidx, wsum);
  } else {
    vq_main<0><<<NBLK, 256, 0, stream>>>(zg, mk, cbg, nullptr, nullptr, nullptr,
                                         outq, outidx, wsum);
  }
  vq_final<<<1, 64, 0, stream>>>(wsum, outls);
}